// Round 1
// baseline (14.921 us; speedup 1.0000x reference)
//
#include <hip/hip_runtime.h>

#define NBATCH 512
#define OUT_U 32
#define OUT_V 128
#define NC 16   // NUM_CTRL
#define PTS_PER_BATCH (OUT_U * OUT_V)   // 4096
#define THREADS 256
#define HALVES 2                         // blocks per batch
#define PTS_PER_THREAD (PTS_PER_BATCH / HALVES / THREADS)  // 8

__global__ __launch_bounds__(THREADS) void surf_eval_kernel(
    const float*  __restrict__ ctrl,   // [512][16][16][4]
    const float*  __restrict__ Nu,     // [32][4]
    const float*  __restrict__ Nv,     // [128][4]
    const int*    __restrict__ uspan,  // [32]
    const int*    __restrict__ vspan,  // [128]
    float*        __restrict__ out)    // [512][32][128][3]
{
    __shared__ float4 sc[NC * NC];      // 4 KB: ctrl_pts[b]
    __shared__ float  sNu[OUT_U][4];    // 512 B
    __shared__ float  sNv[OUT_V][4];    // 2 KB
    __shared__ int    sUs[OUT_U];
    __shared__ int    sVs[OUT_V];

    const int b    = blockIdx.x >> 1;       // batch
    const int half = blockIdx.x & 1;        // which half of the 4096 points
    const int tid  = threadIdx.x;

    // Stage ctrl_pts[b]: 256 float4 = one coalesced float4 per thread.
    const float4* cp = reinterpret_cast<const float4*>(ctrl) + (size_t)b * (NC * NC);
    sc[tid] = cp[tid];

    if (tid < OUT_U) {
        sUs[tid] = uspan[tid] - 3;
        reinterpret_cast<float4*>(&sNu[0][0])[tid] =
            reinterpret_cast<const float4*>(Nu)[tid];
    }
    if (tid < OUT_V) {
        sVs[tid] = vspan[tid] - 3;
        reinterpret_cast<float4*>(&sNv[0][0])[tid] =
            reinterpret_cast<const float4*>(Nv)[tid];
    }
    __syncthreads();

    #pragma unroll
    for (int k = 0; k < PTS_PER_THREAD; ++k) {
        const int pid = half * (PTS_PER_BATCH / HALVES) + k * THREADS + tid;
        const int u = pid >> 7;     // /128
        const int v = pid & 127;

        const int us = sUs[u];
        const int vs = sVs[v];

        const float nu0 = sNu[u][0], nu1 = sNu[u][1], nu2 = sNu[u][2], nu3 = sNu[u][3];
        const float nv0 = sNv[v][0], nv1 = sNv[v][1], nv2 = sNv[v][2], nv3 = sNv[v][3];
        const float nvj[4] = {nv0, nv1, nv2, nv3};
        const float nui[4] = {nu0, nu1, nu2, nu3};

        float ax = 0.f, ay = 0.f, az = 0.f, aw = 0.f;
        #pragma unroll
        for (int i = 0; i < 4; ++i) {
            const int row = (us + i) * NC + vs;
            #pragma unroll
            for (int j = 0; j < 4; ++j) {
                const float w = nui[i] * nvj[j];
                const float4 c = sc[row + j];
                ax = fmaf(w, c.x, ax);
                ay = fmaf(w, c.y, ay);
                az = fmaf(w, c.z, az);
                aw = fmaf(w, c.w, aw);
            }
        }

        const float wclamp = fmaxf(aw, 1e-8f);
        const float inv = 1.0f / wclamp;

        const int o = ((b * OUT_U + u) * OUT_V + v) * 3;
        out[o + 0] = ax * inv;
        out[o + 1] = ay * inv;
        out[o + 2] = az * inv;
    }
}

extern "C" void kernel_launch(void* const* d_in, const int* in_sizes, int n_in,
                              void* d_out, int out_size, void* d_ws, size_t ws_size,
                              hipStream_t stream) {
    const float* ctrl  = (const float*)d_in[0];
    const float* Nu    = (const float*)d_in[1];
    const float* Nv    = (const float*)d_in[2];
    const int*   uspan = (const int*)d_in[3];
    const int*   vspan = (const int*)d_in[4];
    float* out = (float*)d_out;

    dim3 grid(NBATCH * HALVES);   // 1024 blocks
    dim3 block(THREADS);
    hipLaunchKernelGGL(surf_eval_kernel, grid, block, 0, stream,
                       ctrl, Nu, Nv, uspan, vspan, out);
}